// Round 7
// baseline (144.680 us; speedup 1.0000x reference)
//
#include <hip/hip_runtime.h>
#include <hip/hip_fp16.h>
#include <stdint.h>

// ---- types ----
typedef _Float16 h16;
typedef _Float16 h16x8 __attribute__((ext_vector_type(8)));
typedef float f32x4 __attribute__((ext_vector_type(4)));

#define BB 4
#define SS 2048
#define DD 1024

__device__ __forceinline__ void gload16(const void* g, void* l) {
    __builtin_amdgcn_global_load_lds(
        (const __attribute__((address_space(1))) uint32_t*)g,
        (__attribute__((address_space(3))) uint32_t*)l, 16, 0, 0);
}

// ---- fused fp32 -> fp16 convert; every instruction wave-coalesced ----
// Blocks statically partitioned: [0,2048) q, [2048,4096) k, [4096,6144) v,
// [6144,6400) W. Per block: 256 threads x 4 iters x {float4 load -> int2 store},
// iteration stride = 256*16B. Exact coverage, no bounds checks.
__global__ __launch_bounds__(256) void cvt_all(
    const float* __restrict__ q, const float* __restrict__ k,
    const float* __restrict__ v, const float* __restrict__ w,
    h16* __restrict__ qh, h16* __restrict__ kh,
    h16* __restrict__ vh, h16* __restrict__ wh) {
    int b = blockIdx.x;
    const float* src; h16* dst; float sc = 1.0f;
    if (b < 2048)      { src = q; dst = qh; sc = 0.125f; }
    else if (b < 4096) { src = k; dst = kh; b -= 2048; }
    else if (b < 6144) { src = v; dst = vh; b -= 4096; }
    else               { src = w; dst = wh; b -= 6144; }
    size_t base = (size_t)b * 1024 + threadIdx.x;   // float4 index
#pragma unroll
    for (int i = 0; i < 4; ++i) {
        size_t g = base + (size_t)i * 256;
        float4 a = ((const float4*)src)[g];
        union { int2 i2; h16 h[4]; } u;
        u.h[0] = (h16)(a.x * sc); u.h[1] = (h16)(a.y * sc);
        u.h[2] = (h16)(a.z * sc); u.h[3] = (h16)(a.w * sc);
        ((int2*)dst)[g] = u.i2;
    }
}

// ==== 2-phase bt-form GEMM: C[m][n] = sum_k A[m][k]*B[n][k] ====
// 128x128 tile, 4 waves (2Mx2N), 256 thr, 64KB LDS -> 2 blocks/CU.
// m114 desync: two independent blocks per CU co-schedule MFMA and memory
// pipes (one block MFMAs while the other sits at its boundary wait).
// 2-phase counted-vmcnt ledger: stage 8 loads/K-tile (B:4, A-h0:2, A-h1:2);
// mid vmcnt(8) (drains A-h1(G), staged last iter), end vmcnt(2) (leaves
// A-h1(G+1) in flight). Never vmcnt(0) mid-loop.
// T2 granule swizzle: slot s holds global granule s^(r&7) (both-sides, rule 21).
template<bool F32OUT>
__global__ __launch_bounds__(256, 2) void gemm2p_sm(
    const h16* __restrict__ A, const h16* __restrict__ B, void* __restrict__ Cv,
    int lda, int ldb, int ldc, int K, int tilesN, int tilesMN,
    long long aBatch, long long bBatch, long long cBatch)
{
    constexpr int ABYTES = 128 * 128;   // 16 KB
    constexpr int BBYTES = 128 * 128;   // 16 KB
    constexpr int BUFB   = ABYTES + BBYTES;

    __shared__ __align__(1024) char lds[2 * BUFB];   // 64 KB -> 2 blocks/CU

    const int tid = threadIdx.x;
    const int nwg = gridDim.x;
    const int bid = blockIdx.x;
    const int wgid = (bid & 7) * (nwg >> 3) + (bid >> 3);   // XCD swizzle
    const int bb  = wgid / tilesMN;
    const int rem = wgid % tilesMN;
    const int tm = rem / tilesN, tn = rem % tilesN;
    const int row0 = tm * 128, col0 = tn * 128;

    const h16* Ab = A + (long long)bb * aBatch;
    const h16* Bb = B + (long long)bb * bBatch;

    const int lane = tid & 63, wid = tid >> 6;
    const int wm = wid >> 1, wn = wid & 1;     // 2M x 2N, wave tile 64x64
    const int frow = lane & 15, kq = lane >> 4;

    const int NT = K >> 6;

    f32x4 acc[4][4];
#pragma unroll
    for (int m = 0; m < 4; ++m)
#pragma unroll
        for (int n = 0; n < 4; ++n) acc[m][n] = (f32x4){0.f, 0.f, 0.f, 0.f};

    char* l0 = (char*)lds;

    auto STAGE_B = [&](int kt, int buf) {
#pragma unroll
        for (int i = 0; i < 4; ++i) {
            int d = i * 256 + tid;
            int s = d & 7, r = d >> 3;
            int gg = s ^ (r & 7);
            gload16(Bb + (size_t)(col0 + r) * ldb + kt + gg * 8,
                    l0 + buf * BUFB + ABYTES + (r * 8 + s) * 16);
        }
    };
    auto STAGE_AH = [&](int kt, int buf, int mh) {
#pragma unroll
        for (int i = 0; i < 2; ++i) {
            int d = i * 256 + tid;
            int s = d & 7, hr = d >> 3;
            int r = ((hr & ~31) << 1) + mh * 32 + (hr & 31);
            int gg = s ^ (r & 7);
            gload16(Ab + (size_t)(row0 + r) * lda + kt + gg * 8,
                    l0 + buf * BUFB + (r * 8 + s) * 16);
        }
    };
    auto READ_A = [&](int buf, int mh, h16x8 (&af)[2][2]) {
#pragma unroll
        for (int mm = 0; mm < 2; ++mm)
#pragma unroll
            for (int ks = 0; ks < 2; ++ks) {
                int r = wm * 64 + (mh * 2 + mm) * 16 + frow;
                int s = (ks * 4 + kq) ^ (r & 7);
                af[mm][ks] = *(const h16x8*)(l0 + buf * BUFB + (r * 8 + s) * 16);
            }
    };
    auto READ_B = [&](int buf, h16x8 (&bf)[4][2]) {
#pragma unroll
        for (int nn = 0; nn < 4; ++nn)
#pragma unroll
            for (int ks = 0; ks < 2; ++ks) {
                int r = wn * 64 + nn * 16 + frow;
                int s = (ks * 4 + kq) ^ (r & 7);
                bf[nn][ks] = *(const h16x8*)(l0 + buf * BUFB + ABYTES + (r * 8 + s) * 16);
            }
    };
    auto MFMA_H = [&](int mh, h16x8 (&af)[2][2], h16x8 (&bf)[4][2]) {
        __builtin_amdgcn_s_setprio(1);
#pragma unroll
        for (int ks = 0; ks < 2; ++ks)
#pragma unroll
            for (int mm = 0; mm < 2; ++mm)
#pragma unroll
                for (int nn = 0; nn < 4; ++nn)
                    acc[mh * 2 + mm][nn] =
                        __builtin_amdgcn_mfma_f32_16x16x32_f16(
                            af[mm][ks], bf[nn][ks], acc[mh * 2 + mm][nn], 0, 0, 0);
        __builtin_amdgcn_s_setprio(0);
    };

    // prologue: stage tile 0; drain B+A-h0 (leave A-h1(0): 2 loads in flight)
    STAGE_B(0, 0); STAGE_AH(0, 0, 0); STAGE_AH(0, 0, 1);
    asm volatile("s_waitcnt vmcnt(2)" ::: "memory");
    __builtin_amdgcn_s_barrier();

    h16x8 af[2][2], bf[4][2];

    for (int G = 0; G < NT; ++G) {
        const int buf = G & 1;
        const int kt1 = (G + 1) << 6;
        // P0: stage full tile G+1; read A-h0 + B; MFMA mh0
        if (G + 1 < NT) {
            STAGE_B(kt1, buf ^ 1);
            STAGE_AH(kt1, buf ^ 1, 0);
            STAGE_AH(kt1, buf ^ 1, 1);
        }
        READ_A(buf, 0, af);
        READ_B(buf, bf);
        MFMA_H(0, af, bf);
        // mid: drain A-h1(G) (staged last iter); keep tile G+1 (8 loads) in flight
        if (G + 1 < NT) asm volatile("s_waitcnt vmcnt(8)" ::: "memory");
        else            asm volatile("s_waitcnt vmcnt(0)" ::: "memory");
        __builtin_amdgcn_s_barrier();
        // P1: read A-h1; MFMA mh1
        READ_A(buf, 1, af);
        MFMA_H(1, af, bf);
        if (G + 1 >= NT) break;
        // end: drain B(G+1)+A-h0(G+1); leave A-h1(G+1) (2 loads) in flight
        asm volatile("s_waitcnt vmcnt(2)" ::: "memory");
        __builtin_amdgcn_s_barrier();
    }

    const int erow = row0 + wm * 64 + (lane >> 4) * 4;
    const int ecol = col0 + wn * 64 + (lane & 15);
    if (F32OUT) {
        float* C = (float*)Cv + (long long)bb * cBatch;
#pragma unroll
        for (int m = 0; m < 4; ++m)
#pragma unroll
            for (int n = 0; n < 4; ++n)
#pragma unroll
                for (int j = 0; j < 4; ++j)
                    C[(size_t)(erow + m * 16 + j) * ldc + (ecol + n * 16)] = acc[m][n][j];
    } else {
        h16* C = (h16*)Cv + (long long)bb * cBatch;
#pragma unroll
        for (int m = 0; m < 4; ++m)
#pragma unroll
            for (int n = 0; n < 4; ++n)
#pragma unroll
                for (int j = 0; j < 4; ++j)
                    C[(size_t)(erow + m * 16 + j) * ldc + (ecol + n * 16)] = (h16)acc[m][n][j];
    }
}

// ---- row softmax, in place on fp16 rows of length 2048; one block per row ----
__global__ __launch_bounds__(256) void softmax_rows(h16* __restrict__ buf) {
    const int row = blockIdx.x;
    h16* rp = buf + (size_t)row * 2048;
    const int t = threadIdx.x;
    const int lane = t & 63, wid = t >> 6;

    union { int4 i4; h16 h[8]; } u;
    u.i4 = ((const int4*)rp)[t];
    float f[8];
#pragma unroll
    for (int j = 0; j < 8; ++j) f[j] = (float)u.h[j];

    float m = f[0];
#pragma unroll
    for (int j = 1; j < 8; ++j) m = fmaxf(m, f[j]);
#pragma unroll
    for (int off = 32; off; off >>= 1) m = fmaxf(m, __shfl_xor(m, off));

    __shared__ float smax[4];
    __shared__ float ssum[4];
    if (lane == 0) smax[wid] = m;
    __syncthreads();
    m = fmaxf(fmaxf(smax[0], smax[1]), fmaxf(smax[2], smax[3]));

    float s = 0.f;
#pragma unroll
    for (int j = 0; j < 8; ++j) { f[j] = __expf(f[j] - m); s += f[j]; }
#pragma unroll
    for (int off = 32; off; off >>= 1) s += __shfl_xor(s, off);
    if (lane == 0) ssum[wid] = s;
    __syncthreads();
    float inv = 1.0f / (ssum[0] + ssum[1] + ssum[2] + ssum[3]);

#pragma unroll
    for (int j = 0; j < 8; ++j) u.h[j] = (h16)(f[j] * inv);
    ((int4*)rp)[t] = u.i4;
}

extern "C" void kernel_launch(void* const* d_in, const int* in_sizes, int n_in,
                              void* d_out, int out_size, void* d_ws, size_t ws_size,
                              hipStream_t stream) {
    (void)in_sizes; (void)n_in; (void)out_size; (void)ws_size;
    const float* q = (const float*)d_in[0];
    const float* k = (const float*)d_in[1];
    const float* v = (const float*)d_in[2];
    const float* w = (const float*)d_in[3];
    float* out = (float*)d_out;

    const size_t QKV = (size_t)BB * SS * DD;
    h16* qh = (h16*)d_ws;            // 16 MB (reused as vpT after GEMM1 consumes q)
    h16* kh = qh + QKV;              // 16 MB
    h16* vh = kh + QKV;              // 16 MB
    h16* wh = vh + QKV;              // 2 MB
    h16* sc = wh + (size_t)DD * DD;  // scores / P: 33.5 MB

    // 1) fused fp32 -> fp16 (scale 1/sqrt(64)=0.125 folded into q)
    cvt_all<<<6400, 256, 0, stream>>>(q, k, v, w, qh, kh, vh, wh);

    // 2) GEMM1: scores[b][q][k]; M=N=2048, K=1024 per batch.
    //    128x128 tiles: 16x16=256 x 4 batches = 1024 wgs, 2 blocks/CU
    gemm2p_sm<false><<<1024, 256, 0, stream>>>(
        qh, kh, (void*)sc, DD, DD, SS, DD, /*tilesN=*/16, /*tilesMN=*/256,
        (long long)SS * DD, (long long)SS * DD, (long long)SS * SS);

    // 3) softmax rows in place
    softmax_rows<<<BB * SS, 256, 0, stream>>>(sc);

    // 4) GEMM2: vpT[e][s] = sum_d W[e,d]*V[s,d]; M=1024, N=8192, K=1024.
    //    128x128 tiles: 8x64 = 512 wgs
    h16* vpT = qh;
    gemm2p_sm<false><<<512, 256, 0, stream>>>(
        wh, vh, (void*)vpT, DD, DD, BB * SS, DD, /*tilesN=*/64, /*tilesMN=*/512,
        0LL, 0LL, 0LL);

    // 5) GEMM3: Y[b][q][e] = sum_k P[b,q,k]*vpT[e, b*2048+k];
    //    M=2048/batch, N=1024, K=2048. 128x128 tiles: 16x8=128 x 4 batches = 512 wgs
    gemm2p_sm<true><<<512, 256, 0, stream>>>(
        sc, vpT, (void*)out, SS, BB * SS, DD, SS, /*tilesN=*/8, /*tilesMN=*/128,
        (long long)SS * SS, (long long)SS, (long long)SS * DD);
}